// Round 7
// baseline (91.989 us; speedup 1.0000x reference)
//
#include <hip/hip_runtime.h>

// Fully-fused LSA, R7 = R6 with ALL global loads issued upfront (T14 deep
// issue). Model: kernel is outstanding-miss-limited (~300-500K cold lines x
// 0.9us latency / limited in-flight lines per CU ~= the stable ~41us across
// R2-R6). R6 issued ~14 vmem/wave then barrier-serialized the rest; R7 issues
// all 28 (loadA 12, loadB 6, Wv 8, attn 2) before the first drain -> 2x the
// in-flight demand from cycle 0. Everything else (phase skeleton, LDS
// layouts, stencil/GEMM/epilogue index algebra) is byte-identical to the
// R6-verified kernel (absmax 0.125).
//   P0a: issue loadA + attn + loadB + Wv to regs
//   P0b: drain loadA -> hs ring slots 0..7 ; at_s
//   P1 : stencilA + packA -> sv
//   P2 : drain loadB -> slots 0..3 ; Wv -> bf16 -> wvs
//   P3 : gemmA + epilogueA ; stencilB (ring slot (4+yi+dy)&7)
//   P4 : packB   P5: gemmB + epilogueB
// B=4, C=128, H=64, W=128, L=25. LDS 117.2 KB -> 1 block/CU, 8 waves.

namespace {
constexpr int Bn = 4, Cn = 128, Hn = 64, Wn = 128, Ln = 25;
constexpr int HWn = Hn * Wn;  // 8192

constexpr int TX = 16;           // x-tile; block covers 8 output rows (2 halves of 4)
constexpr int HX = 24;           // halo cols (x0-4 .. x0+19)
constexpr int RS = 136;          // hs row stride in halves (272B, 16B-aligned)
constexpr int SVS = 136;         // sv row stride in halves
constexpr int WVS = 136;         // wvs row stride in halves
constexpr int NT = 512;          // threads/block

typedef __attribute__((ext_vector_type(8))) short short8;
typedef __attribute__((ext_vector_type(4))) float f32x4;

__device__ inline unsigned short f2bf(float f) {
    unsigned u = __float_as_uint(f);
    return (unsigned short)((u + 0x7fffu + ((u >> 16) & 1u)) >> 16);  // RNE
}

__global__ __launch_bounds__(NT, 2) void lsa_fused(
    const float* __restrict__ attn, const float* __restrict__ fmap,
    const float* __restrict__ Wv, const float* __restrict__ gamma,
    float* __restrict__ out)
{
    __shared__ alignas(16) unsigned short hs[8 * HX * RS];    // 52.2 KB halo ring
    __shared__ alignas(16) unsigned short sv[64 * SVS];       // 17.4 KB
    __shared__ alignas(16) unsigned short wvs[128 * WVS];     // 34.8 KB
    __shared__ alignas(16) float at_s[2 * 64 * Ln];           // 12.8 KB

    const int tid = threadIdx.x;

    // XCD swizzle for 256 blocks: each XCD gets 32 consecutive logical blocks
    // = one 32-row band of one batch (2 MB fmap slice < 4 MB L2). Bijective.
    const unsigned bid = blockIdx.x;                 // 0..255
    const unsigned logical = (bid & 7u) * 32u + (bid >> 3);
    const int bx  = logical & 7;        // 8 x-tiles
    const int byb = (logical >> 3) & 7; // 8 y-blocks (8 rows each)
    const int b   = logical >> 6;       // 4 batches
    const int x0 = bx * TX;
    const int y0 = byb * 8;

    // ================= P0a: issue ALL global loads to registers =============
    // loadA: halo rows y0-2..y0+5. item i -> (k 0..5, cp 0..63, dy 0..7);
    // quads fully in-range or fully clamped (verbatim R5/R6 map).
    float4 va[6], vb[6];
#pragma unroll
    for (int t = 0; t < 6; ++t) {
        const int i = tid + t * NT;            // 3072 items exactly
        const int k = i % 6;
        const int r = i / 6;
        const int cp = r & 63;
        const int dy = r >> 6;
        const int ry = min(max(y0 + dy - 2, 0), Hn - 1);
        const int gxb = x0 - 4 + 4 * k;
        const size_t rowb = ((size_t)(b * Cn + 2 * cp)) * HWn + (size_t)ry * Wn;
        if (gxb < 0) {                       // only bx==0, k==0: replicate col 0
            const float s0 = fmap[rowb], s1 = fmap[rowb + HWn];
            va[t].x = va[t].y = va[t].z = va[t].w = s0;
            vb[t].x = vb[t].y = vb[t].z = vb[t].w = s1;
        } else if (gxb > Wn - 4) {           // only bx==7, k==5: replicate col W-1
            const float s0 = fmap[rowb + Wn - 1], s1 = fmap[rowb + HWn + Wn - 1];
            va[t].x = va[t].y = va[t].z = va[t].w = s0;
            vb[t].x = vb[t].y = vb[t].z = vb[t].w = s1;
        } else {
            va[t] = *(const float4*)&fmap[rowb + gxb];
            vb[t] = *(const float4*)&fmap[rowb + HWn + gxb];
        }
    }
    // attn, both halves: 800 float4 linear.
    const size_t ab = ((size_t)b * HWn + (size_t)y0 * Wn + x0) * Ln;
    float4 at0, at1;
    {
        const int i4 = tid;                    // < 800 always
        const int h = i4 / 400, rem = i4 - h * 400;
        const int yia = rem / 100, j4 = (rem - yia * 100) * 4;
        at0 = *(const float4*)&attn[ab + (size_t)h * 12800 + (size_t)yia * 3200 + j4];
    }
    if (tid < 288) {
        const int i4 = tid + 512;              // 512..799
        const int h = i4 / 400, rem = i4 - h * 400;
        const int yia = rem / 100, j4 = (rem - yia * 100) * 4;
        at1 = *(const float4*)&attn[ab + (size_t)h * 12800 + (size_t)yia * 3200 + j4];
    }
    // loadB: halo rows y0+6..y0+9 (item j -> (k, cp, dyp 0..3))
    float4 va2[3], vb2[3];
#pragma unroll
    for (int t = 0; t < 3; ++t) {
        const int j = tid + t * NT;            // 1536 items
        const int k = j % 6;
        const int r = j / 6;
        const int cp = r & 63;
        const int dyp = r >> 6;
        const int ry = min(y0 + 6 + dyp, Hn - 1);   // lower clamp impossible
        const int gxb = x0 - 4 + 4 * k;
        const size_t rowb = ((size_t)(b * Cn + 2 * cp)) * HWn + (size_t)ry * Wn;
        if (gxb < 0) {
            const float s0 = fmap[rowb], s1 = fmap[rowb + HWn];
            va2[t].x = va2[t].y = va2[t].z = va2[t].w = s0;
            vb2[t].x = vb2[t].y = vb2[t].z = vb2[t].w = s1;
        } else if (gxb > Wn - 4) {
            const float s0 = fmap[rowb + Wn - 1], s1 = fmap[rowb + HWn + Wn - 1];
            va2[t].x = va2[t].y = va2[t].z = va2[t].w = s0;
            vb2[t].x = vb2[t].y = vb2[t].z = vb2[t].w = s1;
        } else {
            va2[t] = *(const float4*)&fmap[rowb + gxb];
            vb2[t] = *(const float4*)&fmap[rowb + HWn + gxb];
        }
    }
    // Wv: 8 float4/thread = full 128x128 f32
    float4 wq[8];
#pragma unroll
    for (int t = 0; t < 8; ++t)
        wq[t] = *(const float4*)&Wv[(size_t)(tid + t * NT) * 4];

    // ================= P0b: drain loadA -> hs ring + at_s ===================
#pragma unroll
    for (int t = 0; t < 6; ++t) {
        const int i = tid + t * NT;
        const int k = i % 6;
        const int r = i / 6;
        const int cp = r & 63;
        const int dy = r >> 6;
        unsigned short* hbase = &hs[(dy * HX + 4 * k) * RS + 2 * cp];
        *(unsigned*)&hbase[0 * RS] = (unsigned)f2bf(va[t].x) | ((unsigned)f2bf(vb[t].x) << 16);
        *(unsigned*)&hbase[1 * RS] = (unsigned)f2bf(va[t].y) | ((unsigned)f2bf(vb[t].y) << 16);
        *(unsigned*)&hbase[2 * RS] = (unsigned)f2bf(va[t].z) | ((unsigned)f2bf(vb[t].z) << 16);
        *(unsigned*)&hbase[3 * RS] = (unsigned)f2bf(va[t].w) | ((unsigned)f2bf(vb[t].w) << 16);
    }
    *(float4*)&at_s[tid * 4] = at0;
    if (tid < 288) *(float4*)&at_s[(tid + 512) * 4] = at1;
    __syncthreads();  // B1

    // ================= P1: stencilA + packA (verbatim) ======================
    const int xi = tid & 15, kq = (tid >> 4) & 7, yi = tid >> 7;
    const int p = yi * 16 + xi;
    float acc[16];
#pragma unroll
    for (int j = 0; j < 16; ++j) acc[j] = 0.f;

#pragma unroll
    for (int l = 0; l < Ln; ++l) {
        const int dy = l / 5, dx = l % 5;
        const float a = at_s[p * Ln + l];
        const unsigned short* row = &hs[((yi + dy) * HX + (2 + xi + dx)) * RS + kq * 16];
#pragma unroll
        for (int q = 0; q < 2; ++q) {
            uint4 u = *(const uint4*)&row[q * 8];
            const unsigned w[4] = {u.x, u.y, u.z, u.w};
#pragma unroll
            for (int e = 0; e < 4; ++e) {
                acc[q * 8 + 2 * e + 0] += a * __uint_as_float(w[e] << 16);
                acc[q * 8 + 2 * e + 1] += a * __uint_as_float(w[e] & 0xffff0000u);
            }
        }
    }
    {
        unsigned short* dst = &sv[p * SVS + kq * 16];
#pragma unroll
        for (int q = 0; q < 2; ++q) {
            unsigned pk[4];
#pragma unroll
            for (int e = 0; e < 4; ++e)
                pk[e] = (unsigned)f2bf(acc[q * 8 + 2 * e]) |
                        ((unsigned)f2bf(acc[q * 8 + 2 * e + 1]) << 16);
            uint4 v; v.x = pk[0]; v.y = pk[1]; v.z = pk[2]; v.w = pk[3];
            *(uint4*)&dst[q * 8] = v;
        }
    }
    __syncthreads();  // B2: stencilA hs reads done -> slots 0..3 reusable

    // ================= P2: drainB -> slots 0..3 ; Wv -> wvs =================
#pragma unroll
    for (int t = 0; t < 3; ++t) {
        const int j = tid + t * NT;
        const int k = j % 6;
        const int r = j / 6;
        const int cp = r & 63;
        const int dyp = r >> 6;                // slot = (8+dyp)&7 = dyp
        unsigned short* hbase = &hs[(dyp * HX + 4 * k) * RS + 2 * cp];
        *(unsigned*)&hbase[0 * RS] = (unsigned)f2bf(va2[t].x) | ((unsigned)f2bf(vb2[t].x) << 16);
        *(unsigned*)&hbase[1 * RS] = (unsigned)f2bf(va2[t].y) | ((unsigned)f2bf(vb2[t].y) << 16);
        *(unsigned*)&hbase[2 * RS] = (unsigned)f2bf(va2[t].z) | ((unsigned)f2bf(vb2[t].z) << 16);
        *(unsigned*)&hbase[3 * RS] = (unsigned)f2bf(va2[t].w) | ((unsigned)f2bf(vb2[t].w) << 16);
    }
#pragma unroll
    for (int t = 0; t < 8; ++t) {
        const int i4 = tid + t * NT;           // float4 index within Wv
        const int r = i4 >> 5;
        const int c = (i4 & 31) * 4;
        uint2 v;
        v.x = (unsigned)f2bf(wq[t].x) | ((unsigned)f2bf(wq[t].y) << 16);
        v.y = (unsigned)f2bf(wq[t].z) | ((unsigned)f2bf(wq[t].w) << 16);
        *(uint2*)&wvs[r * WVS + c] = v;
    }
    __syncthreads();  // B3

    // ================= P3: gemmA + epilogueA ; stencilB =====================
    const int wave = tid >> 6, lane = tid & 63;
    const int m16 = lane & 15, q = lane >> 4;
    const int wrow = wave >> 1;
    const int mhalf = wave & 1;
    const float g = gamma[0];

    {
        const int n = (y0 + wrow) * Wn + x0 + m16;
        short8 bfrag[4];
        const unsigned short* srow = &sv[(wrow * 16 + m16) * SVS + q * 8];
#pragma unroll
        for (int kk = 0; kk < 4; ++kk) bfrag[kk] = *(const short8*)(srow + kk * 32);
        f32x4 accv[4];
#pragma unroll
        for (int t = 0; t < 4; ++t) { f32x4 z = {0.f, 0.f, 0.f, 0.f}; accv[t] = z; }
#pragma unroll
        for (int t = 0; t < 4; ++t) {
            const int mg = mhalf * 4 + t;
            const unsigned short* arow = &wvs[(mg * 16 + m16) * WVS + q * 8];
#pragma unroll
            for (int kk = 0; kk < 4; ++kk) {
                short8 af = *(const short8*)(arow + kk * 32);
                accv[t] = __builtin_amdgcn_mfma_f32_16x16x32_bf16(af, bfrag[kk], accv[t], 0, 0, 0);
            }
        }
#pragma unroll
        for (int t = 0; t < 4; ++t) {
            const int mg = mhalf * 4 + t;
#pragma unroll
            for (int r = 0; r < 4; ++r) {
                const int c = mg * 16 + q * 4 + r;
                const size_t idx = ((size_t)(b * Cn + c)) * HWn + n;
                out[idx] = fmap[idx] + g * accv[t][r];
            }
        }
    }

    // stencilB: ring slot = (4 + yi + dy) & 7; attn from half-1 region.
#pragma unroll
    for (int j = 0; j < 16; ++j) acc[j] = 0.f;
#pragma unroll
    for (int l = 0; l < Ln; ++l) {
        const int dy = l / 5, dx = l % 5;
        const float a = at_s[1600 + p * Ln + l];
        const unsigned short* row = &hs[((((4 + yi + dy) & 7)) * HX + (2 + xi + dx)) * RS + kq * 16];
#pragma unroll
        for (int q2 = 0; q2 < 2; ++q2) {
            uint4 u = *(const uint4*)&row[q2 * 8];
            const unsigned w[4] = {u.x, u.y, u.z, u.w};
#pragma unroll
            for (int e = 0; e < 4; ++e) {
                acc[q2 * 8 + 2 * e + 0] += a * __uint_as_float(w[e] << 16);
                acc[q2 * 8 + 2 * e + 1] += a * __uint_as_float(w[e] & 0xffff0000u);
            }
        }
    }
    __syncthreads();  // B4: gemmA sv reads done

    // ================= P4: packB -> sv ======================================
    {
        unsigned short* dst = &sv[p * SVS + kq * 16];
#pragma unroll
        for (int q2 = 0; q2 < 2; ++q2) {
            unsigned pk[4];
#pragma unroll
            for (int e = 0; e < 4; ++e)
                pk[e] = (unsigned)f2bf(acc[q2 * 8 + 2 * e]) |
                        ((unsigned)f2bf(acc[q2 * 8 + 2 * e + 1]) << 16);
            uint4 v; v.x = pk[0]; v.y = pk[1]; v.z = pk[2]; v.w = pk[3];
            *(uint4*)&dst[q2 * 8] = v;
        }
    }
    __syncthreads();  // B5

    // ================= P5: gemmB + epilogueB ================================
    {
        const int n = (y0 + 4 + wrow) * Wn + x0 + m16;
        short8 bfrag[4];
        const unsigned short* srow = &sv[(wrow * 16 + m16) * SVS + q * 8];
#pragma unroll
        for (int kk = 0; kk < 4; ++kk) bfrag[kk] = *(const short8*)(srow + kk * 32);
        f32x4 accv[4];
#pragma unroll
        for (int t = 0; t < 4; ++t) { f32x4 z = {0.f, 0.f, 0.f, 0.f}; accv[t] = z; }
#pragma unroll
        for (int t = 0; t < 4; ++t) {
            const int mg = mhalf * 4 + t;
            const unsigned short* arow = &wvs[(mg * 16 + m16) * WVS + q * 8];
#pragma unroll
            for (int kk = 0; kk < 4; ++kk) {
                short8 af = *(const short8*)(arow + kk * 32);
                accv[t] = __builtin_amdgcn_mfma_f32_16x16x32_bf16(af, bfrag[kk], accv[t], 0, 0, 0);
            }
        }
#pragma unroll
        for (int t = 0; t < 4; ++t) {
            const int mg = mhalf * 4 + t;
#pragma unroll
            for (int r = 0; r < 4; ++r) {
                const int c = mg * 16 + q * 4 + r;
                const size_t idx = ((size_t)(b * Cn + c)) * HWn + n;
                out[idx] = fmap[idx] + g * accv[t][r];
            }
        }
    }
}
}  // namespace

extern "C" void kernel_launch(void* const* d_in, const int* in_sizes, int n_in,
                              void* d_out, int out_size, void* d_ws, size_t ws_size,
                              hipStream_t stream) {
    const float* attn  = (const float*)d_in[0];
    const float* fmap  = (const float*)d_in[1];
    const float* Wv    = (const float*)d_in[2];
    const float* gamma = (const float*)d_in[3];
    float* out = (float*)d_out;

    lsa_fused<<<dim3(256), NT, 0, stream>>>(attn, fmap, Wv, gamma, out);
}

// Round 8
// 86.942 us; speedup vs baseline: 1.0580x; 1.0580x over previous
//
#include <hip/hip_runtime.h>

// Fully-fused LSA, R8: the 5x5 stencil becomes MFMA. R7 counters: traffic
// near-minimal (FETCH 10.7MB), HBM 7%, VALU 13%, Mfma 1% -> kernel is bound
// by per-CU DS+VALU instruction work (stencil = ~925 VALU + 75 DS per thread,
// ~75% of dynamic work). Reformulate per pixel-row:
//   S(16x128) = M(16x192) @ R(192x128),  k = slot*24 + hcol,
//   Rt[ch][k] = f16(halo[slot][hcol][ch])          (channel-major halo)
//   M[xi][k]  = f16(attn[p][dy*5+dx]) at k=(yi+dy)*24+2+xi+dx, else 0
// Fragment layouts copied 1:1 from the VERIFIED Wv-GEMM (lane m16 -> row/col,
// k = q*8+kk*32 contiguous short8). Stencil inputs f16 (>= bf16 precision,
// 1-op cvt). Halo load map, Wv-GEMM, epilogue verbatim R5 (absmax 0.125).
// LDS overlays: Rt(51.2K)->wvs(34.8K), M(25.6K)->sv(17.4K): 76.8KB, 2 blk/CU.
//   P0: issue halo(12 f4)+attn(1 f4); drain halo->Rt f16; zero M     B1
//   P1: scatter attn->M (400 thr)                                    B2
//   P2: issue Wv f32; stencil-MFMA (f16): acv[4] per wave            B3
//   P3: sv(bf16) <- acv ; wvs(bf16) <- Wv                            B4
//   P4: Wv-GEMM (bf16 MFMA) + residual epilogue
// B=4, C=128, H=64, W=128, L=25. Grid 512, NT=512, XCD-swizzled.

namespace {
constexpr int Bn = 4, Cn = 128, Hn = 64, Wn = 128, Ln = 25;
constexpr int HWn = Hn * Wn;  // 8192

constexpr int TX = 16, TY = 4;   // 64 px per block
constexpr int RTS = 200;         // Rt row stride in shorts (K=192 + pad, 400B: 16B-aligned)
constexpr int MS  = 200;         // M row stride in shorts
constexpr int SVS = 136;         // sv row stride (verbatim R5)
constexpr int WVS = 136;         // wvs row stride (verbatim R5)
constexpr int NT  = 512;

typedef __attribute__((ext_vector_type(8))) short short8;
typedef _Float16 half8 __attribute__((ext_vector_type(8)));
typedef __attribute__((ext_vector_type(4))) float f32x4;

__device__ inline unsigned short f2bf(float f) {
    unsigned u = __float_as_uint(f);
    return (unsigned short)((u + 0x7fffu + ((u >> 16) & 1u)) >> 16);  // RNE
}
__device__ inline unsigned short f2h(float f) {
    union { _Float16 h; unsigned short u; } c; c.h = (_Float16)f; return c.u;
}
__device__ inline unsigned pk2h(float a, float b) {
    return (unsigned)f2h(a) | ((unsigned)f2h(b) << 16);
}

__global__ __launch_bounds__(NT, 4) void lsa_fused(
    const float* __restrict__ attn, const float* __restrict__ fmap,
    const float* __restrict__ Wv, const float* __restrict__ gamma,
    float* __restrict__ out)
{
    // region A: Rt f16 [128][200] (51.2KB) -> later wvs bf16 [128][136]
    // region B: M  f16 [4][16][200] (25.6KB) -> later sv bf16 [64][136]
    __shared__ alignas(16) unsigned short smem[38400];  // 76.8 KB
    unsigned short* const Rt = smem;
    unsigned short* const Mb = smem + 25600;

    const int tid = threadIdx.x;

    // XCD swizzle (verbatim R5): each XCD gets 64 consecutive logical blocks
    // = one batch x 32-row band (2.4MB fmap slice < 4MB L2). Bijective.
    const unsigned bid = blockIdx.x;                 // 0..511
    const unsigned logical = (bid & 7u) * 64u + (bid >> 3);
    const int bx  = logical & 7;        // 8 x-tiles
    const int byz = logical >> 3;
    const int by  = byz & 15;           // 16 y-tiles
    const int b   = byz >> 4;           // 4 batches
    const int x0 = bx * TX;
    const int y0 = by * TY;

    // ---- P0a: issue halo loads (verbatim R5 map: (k6,cp,slot)) ----
    float4 va[6], vb[6];
#pragma unroll
    for (int t = 0; t < 6; ++t) {
        const int i = tid + t * NT;            // 3072 items exactly
        const int k6 = i % 6;
        const int r = i / 6;
        const int cp = r & 63;
        const int s = r >> 6;                  // halo slot 0..7, row y0+s-2
        const int ry = min(max(y0 + s - 2, 0), Hn - 1);
        const int gxb = x0 - 4 + 4 * k6;
        const size_t rowb = ((size_t)(b * Cn + 2 * cp)) * HWn + (size_t)ry * Wn;
        if (gxb < 0) {                       // only bx==0, k6==0: replicate col 0
            const float s0 = fmap[rowb], s1 = fmap[rowb + HWn];
            va[t].x = va[t].y = va[t].z = va[t].w = s0;
            vb[t].x = vb[t].y = vb[t].z = vb[t].w = s1;
        } else if (gxb > Wn - 4) {           // only bx==7, k6==5: replicate col W-1
            const float s0 = fmap[rowb + Wn - 1], s1 = fmap[rowb + HWn + Wn - 1];
            va[t].x = va[t].y = va[t].z = va[t].w = s0;
            vb[t].x = vb[t].y = vb[t].z = vb[t].w = s1;
        } else {
            va[t] = *(const float4*)&fmap[rowb + gxb];
            vb[t] = *(const float4*)&fmap[rowb + HWn + gxb];
        }
    }
    // attn: 400 float4 linear (verbatim R5 addressing)
    const size_t ab = ((size_t)b * HWn + (size_t)y0 * Wn + x0) * Ln;
    float4 at_r;
    const int yia = tid / 100, j4 = tid - yia * 100;
    if (tid < 400)
        at_r = *(const float4*)&attn[ab + (size_t)yia * (Wn * Ln) + (size_t)j4 * 4];

    // ---- P0b: drain halo -> Rt (f16, channel-major) ; zero M ----
#pragma unroll
    for (int t = 0; t < 6; ++t) {
        const int i = tid + t * NT;
        const int k6 = i % 6;
        const int r = i / 6;
        const int cp = r & 63;
        const int s = r >> 6;
        unsigned short* d0 = &Rt[(2 * cp) * RTS + s * 24 + 4 * k6];
        uint2 wa; wa.x = pk2h(va[t].x, va[t].y); wa.y = pk2h(va[t].z, va[t].w);
        uint2 wb; wb.x = pk2h(vb[t].x, vb[t].y); wb.y = pk2h(vb[t].z, vb[t].w);
        *(uint2*)d0 = wa;
        *(uint2*)(d0 + RTS) = wb;
    }
    {
        const uint4 z4 = {0u, 0u, 0u, 0u};
        for (int i = tid; i < 1600; i += NT)   // 1600 uint4 = 25.6KB
            *(uint4*)&Mb[i * 8] = z4;
    }
    __syncthreads();  // B1: M zeroed, Rt staged

    // ---- P1: scatter attn -> M (banded matrix, f16) ----
    if (tid < 400) {
        const float ae[4] = {at_r.x, at_r.y, at_r.z, at_r.w};
#pragma unroll
        for (int e = 0; e < 4; ++e) {
            const int t2 = j4 * 4 + e;          // 0..399 within row yia
            const int xi2 = t2 / 25, l = t2 - 25 * xi2;
            const int dy = l / 5, dx = l - 5 * dy;
            // k = (yi+dy)*24 + 2 + xi + dx  (slot s=yi+dy holds row y0+s-2)
            Mb[(yia * 16 + xi2) * MS + (yia + dy) * 24 + 2 + xi2 + dx] = f2h(ae[e]);
        }
    }
    __syncthreads();  // B2: M ready

    // ---- P2: issue Wv f32; stencil-MFMA ----
    float4 wq[8];
#pragma unroll
    for (int t = 0; t < 8; ++t)
        wq[t] = *(const float4*)&Wv[(size_t)(tid + t * NT) * 4];

    const int wave = tid >> 6, lane = tid & 63;
    const int m16 = lane & 15, q = lane >> 4;
    const int row = wave >> 1;            // pixel row 0..3
    const int chalf = wave & 1;           // 64-channel half

    f32x4 acv[4];
#pragma unroll
    for (int t = 0; t < 4; ++t) { f32x4 z = {0.f, 0.f, 0.f, 0.f}; acv[t] = z; }

    // D[row=c_in_tile (q*4+reg)][col=xi (m16)]; A = Rt rows (ch), B = M rows (xi)
#pragma unroll
    for (int kk = 0; kk < 6; ++kk) {
        half8 bfr = *(const half8*)&Mb[(row * 16 + m16) * MS + q * 8 + kk * 32];
#pragma unroll
        for (int ct = 0; ct < 4; ++ct) {
            half8 af = *(const half8*)&Rt[(chalf * 64 + ct * 16 + m16) * RTS + q * 8 + kk * 32];
            acv[ct] = __builtin_amdgcn_mfma_f32_16x16x32_f16(af, bfr, acv[ct], 0, 0, 0);
        }
    }
    __syncthreads();  // B3: Rt, M dead

    // ---- P3: sv (bf16) <- acv into M region ; wvs (bf16) <- wq into Rt region ----
    unsigned short* const sv  = Mb;
    unsigned short* const wvs = Rt;
    {
        const int px = row * 16 + m16;
#pragma unroll
        for (int ct = 0; ct < 4; ++ct) {
            const int c0 = chalf * 64 + ct * 16 + q * 4;   // c = c0 + reg
            uint2 w;
            w.x = (unsigned)f2bf(acv[ct][0]) | ((unsigned)f2bf(acv[ct][1]) << 16);
            w.y = (unsigned)f2bf(acv[ct][2]) | ((unsigned)f2bf(acv[ct][3]) << 16);
            *(uint2*)&sv[px * SVS + c0] = w;
        }
    }
#pragma unroll
    for (int t = 0; t < 8; ++t) {
        const int i4 = tid + t * NT;           // float4 index within Wv
        const int rr = i4 >> 5;                // row (32 float4 per 128-col row)
        const int cc = (i4 & 31) * 4;
        uint2 v;
        v.x = (unsigned)f2bf(wq[t].x) | ((unsigned)f2bf(wq[t].y) << 16);
        v.y = (unsigned)f2bf(wq[t].z) | ((unsigned)f2bf(wq[t].w) << 16);
        *(uint2*)&wvs[rr * WVS + cc] = v;
    }
    __syncthreads();  // B4

    // ---- P4: Wv-GEMM + residual epilogue (verbatim R5, verified) ----
    const int n = (y0 + row) * Wn + x0 + m16;
    const float g = gamma[0];

    short8 bfrag[4];
    {
        const unsigned short* srow = &sv[(row * 16 + m16) * SVS + q * 8];
#pragma unroll
        for (int kk = 0; kk < 4; ++kk) bfrag[kk] = *(const short8*)(srow + kk * 32);
    }
    f32x4 accv[4];
#pragma unroll
    for (int t = 0; t < 4; ++t) { f32x4 z = {0.f, 0.f, 0.f, 0.f}; accv[t] = z; }

#pragma unroll
    for (int t = 0; t < 4; ++t) {
        const int mg = chalf * 4 + t;
        const unsigned short* arow = &wvs[(mg * 16 + m16) * WVS + q * 8];
#pragma unroll
        for (int kk = 0; kk < 4; ++kk) {
            short8 af = *(const short8*)(arow + kk * 32);
            accv[t] = __builtin_amdgcn_mfma_f32_16x16x32_bf16(af, bfrag[kk], accv[t], 0, 0, 0);
        }
    }
#pragma unroll
    for (int t = 0; t < 4; ++t) {
        const int mg = chalf * 4 + t;
#pragma unroll
        for (int r = 0; r < 4; ++r) {
            const int c = mg * 16 + q * 4 + r;
            const size_t idx = ((size_t)(b * Cn + c)) * HWn + n;
            out[idx] = fmap[idx] + g * accv[t][r];
        }
    }
}
}  // namespace

extern "C" void kernel_launch(void* const* d_in, const int* in_sizes, int n_in,
                              void* d_out, int out_size, void* d_ws, size_t ws_size,
                              hipStream_t stream) {
    const float* attn  = (const float*)d_in[0];
    const float* fmap  = (const float*)d_in[1];
    const float* Wv    = (const float*)d_in[2];
    const float* gamma = (const float*)d_in[3];
    float* out = (float*)d_out;

    lsa_fused<<<dim3(512), NT, 0, stream>>>(attn, fmap, Wv, gamma, out);
}

// Round 10
// 86.248 us; speedup vs baseline: 1.0666x; 1.0080x over previous
//
#include <hip/hip_runtime.h>

// Fully-fused LSA, R10 = R9 with the compile fix: __builtin_nontemporal_load
// requires a Clang ext-vector pointer (not HIP's struct float4) -> attn NT
// load goes through f32x4. Logic identical to R9:
//  (1) Non-temporal `out` stores + `attn` load (single-touch data; avoid
//      allocating ~20MB in dirty-poisoned L3 -> fewer eviction writebacks).
//  (2) Row-dependent kk-trim in stencil MFMA: kk in [max(0,r-1), min(5,r+3)]
//      (M is zero outside the band; skip exact). -25% MFMA/ds_read.
// Structure (R8-verified, absmax 0.125):
//   P0: issue halo(12 f4)+attn(1 f4 NT); drain halo->Rt f16; zero M   B1
//   P1: scatter attn->M (400 thr)                                     B2
//   P2: issue Wv f32; stencil-MFMA f16 (kk-trimmed)                   B3
//   P3: sv(bf16) <- acv ; wvs(bf16) <- Wv                             B4
//   P4: Wv-GEMM (bf16 MFMA) + residual epilogue (NT stores)
// B=4, C=128, H=64, W=128, L=25. Grid 512, NT=512, XCD-swizzled,
// LDS 76.8KB -> 2 blocks/CU.

namespace {
constexpr int Bn = 4, Cn = 128, Hn = 64, Wn = 128, Ln = 25;
constexpr int HWn = Hn * Wn;  // 8192

constexpr int TX = 16, TY = 4;   // 64 px per block
constexpr int RTS = 200;         // Rt row stride in shorts (K=192 + pad)
constexpr int MS  = 200;         // M row stride in shorts
constexpr int SVS = 136;         // sv row stride (verbatim R5)
constexpr int WVS = 136;         // wvs row stride (verbatim R5)
constexpr int NT  = 512;

typedef __attribute__((ext_vector_type(8))) short short8;
typedef _Float16 half8 __attribute__((ext_vector_type(8)));
typedef __attribute__((ext_vector_type(4))) float f32x4;

__device__ inline unsigned short f2bf(float f) {
    unsigned u = __float_as_uint(f);
    return (unsigned short)((u + 0x7fffu + ((u >> 16) & 1u)) >> 16);  // RNE
}
__device__ inline unsigned short f2h(float f) {
    union { _Float16 h; unsigned short u; } c; c.h = (_Float16)f; return c.u;
}
__device__ inline unsigned pk2h(float a, float b) {
    return (unsigned)f2h(a) | ((unsigned)f2h(b) << 16);
}

__global__ __launch_bounds__(NT, 4) void lsa_fused(
    const float* __restrict__ attn, const float* __restrict__ fmap,
    const float* __restrict__ Wv, const float* __restrict__ gamma,
    float* __restrict__ out)
{
    // region A: Rt f16 [128][200] (51.2KB) -> later wvs bf16 [128][136]
    // region B: M  f16 [4][16][200] (25.6KB) -> later sv bf16 [64][136]
    __shared__ alignas(16) unsigned short smem[38400];  // 76.8 KB
    unsigned short* const Rt = smem;
    unsigned short* const Mb = smem + 25600;

    const int tid = threadIdx.x;

    // XCD swizzle (verbatim R5): each XCD gets 64 consecutive logical blocks
    // = one batch x 32-row band (2.4MB fmap slice < 4MB L2). Bijective.
    const unsigned bid = blockIdx.x;                 // 0..511
    const unsigned logical = (bid & 7u) * 64u + (bid >> 3);
    const int bx  = logical & 7;        // 8 x-tiles
    const int byz = logical >> 3;
    const int by  = byz & 15;           // 16 y-tiles
    const int b   = byz >> 4;           // 4 batches
    const int x0 = bx * TX;
    const int y0 = by * TY;

    // ---- P0a: issue halo loads (verbatim R5 map: (k6,cp,slot)) ----
    float4 va[6], vb[6];
#pragma unroll
    for (int t = 0; t < 6; ++t) {
        const int i = tid + t * NT;            // 3072 items exactly
        const int k6 = i % 6;
        const int r = i / 6;
        const int cp = r & 63;
        const int s = r >> 6;                  // halo slot 0..7, row y0+s-2
        const int ry = min(max(y0 + s - 2, 0), Hn - 1);
        const int gxb = x0 - 4 + 4 * k6;
        const size_t rowb = ((size_t)(b * Cn + 2 * cp)) * HWn + (size_t)ry * Wn;
        if (gxb < 0) {                       // only bx==0, k6==0: replicate col 0
            const float s0 = fmap[rowb], s1 = fmap[rowb + HWn];
            va[t].x = va[t].y = va[t].z = va[t].w = s0;
            vb[t].x = vb[t].y = vb[t].z = vb[t].w = s1;
        } else if (gxb > Wn - 4) {           // only bx==7, k6==5: replicate col W-1
            const float s0 = fmap[rowb + Wn - 1], s1 = fmap[rowb + HWn + Wn - 1];
            va[t].x = va[t].y = va[t].z = va[t].w = s0;
            vb[t].x = vb[t].y = vb[t].z = vb[t].w = s1;
        } else {
            va[t] = *(const float4*)&fmap[rowb + gxb];
            vb[t] = *(const float4*)&fmap[rowb + HWn + gxb];
        }
    }
    // attn: 400 float4 linear, non-temporal (single-touch; keep out of L3).
    // NT builtin needs an ext-vector pointer -> use f32x4.
    const size_t ab = ((size_t)b * HWn + (size_t)y0 * Wn + x0) * Ln;
    f32x4 at_r;
    const int yia = tid / 100, j4 = tid - yia * 100;
    if (tid < 400)
        at_r = __builtin_nontemporal_load(
            (const f32x4*)&attn[ab + (size_t)yia * (Wn * Ln) + (size_t)j4 * 4]);

    // ---- P0b: drain halo -> Rt (f16, channel-major) ; zero M ----
#pragma unroll
    for (int t = 0; t < 6; ++t) {
        const int i = tid + t * NT;
        const int k6 = i % 6;
        const int r = i / 6;
        const int cp = r & 63;
        const int s = r >> 6;
        unsigned short* d0 = &Rt[(2 * cp) * RTS + s * 24 + 4 * k6];
        uint2 wa; wa.x = pk2h(va[t].x, va[t].y); wa.y = pk2h(va[t].z, va[t].w);
        uint2 wb; wb.x = pk2h(vb[t].x, vb[t].y); wb.y = pk2h(vb[t].z, vb[t].w);
        *(uint2*)d0 = wa;
        *(uint2*)(d0 + RTS) = wb;
    }
    {
        const uint4 z4 = {0u, 0u, 0u, 0u};
        for (int i = tid; i < 1600; i += NT)   // 1600 uint4 = 25.6KB
            *(uint4*)&Mb[i * 8] = z4;
    }
    __syncthreads();  // B1: M zeroed, Rt staged

    // ---- P1: scatter attn -> M (banded matrix, f16) ----
    if (tid < 400) {
        const float ae[4] = {at_r[0], at_r[1], at_r[2], at_r[3]};
#pragma unroll
        for (int e = 0; e < 4; ++e) {
            const int t2 = j4 * 4 + e;          // 0..399 within row yia
            const int xi2 = t2 / 25, l = t2 - 25 * xi2;
            const int dy = l / 5, dx = l - 5 * dy;
            // k = (yi+dy)*24 + 2 + xi + dx  (slot s=yi+dy holds row y0+s-2)
            Mb[(yia * 16 + xi2) * MS + (yia + dy) * 24 + 2 + xi2 + dx] = f2h(ae[e]);
        }
    }
    __syncthreads();  // B2: M ready

    // ---- P2: issue Wv f32; stencil-MFMA (kk-trimmed) ----
    float4 wq[8];
#pragma unroll
    for (int t = 0; t < 8; ++t)
        wq[t] = *(const float4*)&Wv[(size_t)(tid + t * NT) * 4];

    const int wave = tid >> 6, lane = tid & 63;
    const int m16 = lane & 15, q = lane >> 4;
    const int row = wave >> 1;            // pixel row 0..3
    const int chalf = wave & 1;           // 64-channel half

    f32x4 acv[4];
#pragma unroll
    for (int t = 0; t < 4; ++t) { f32x4 z = {0.f, 0.f, 0.f, 0.f}; acv[t] = z; }

    // Band for row r: k in [24r+2, 24r+117] -> kk in [max(0,r-1), min(5,r+3)].
    // M is zero outside the band, so skipping those kk is exact.
    const int kk0 = max(0, row - 1);
    const int kk1 = min(5, row + 3);
#pragma unroll
    for (int kk = 0; kk < 6; ++kk) {
        if (kk >= kk0 && kk <= kk1) {        // wave-uniform guard
            half8 bfr = *(const half8*)&Mb[(row * 16 + m16) * MS + q * 8 + kk * 32];
#pragma unroll
            for (int ct = 0; ct < 4; ++ct) {
                half8 af = *(const half8*)&Rt[(chalf * 64 + ct * 16 + m16) * RTS + q * 8 + kk * 32];
                acv[ct] = __builtin_amdgcn_mfma_f32_16x16x32_f16(af, bfr, acv[ct], 0, 0, 0);
            }
        }
    }
    __syncthreads();  // B3: Rt, M dead

    // ---- P3: sv (bf16) <- acv into M region ; wvs (bf16) <- wq into Rt region ----
    unsigned short* const sv  = Mb;
    unsigned short* const wvs = Rt;
    {
        const int px = row * 16 + m16;
#pragma unroll
        for (int ct = 0; ct < 4; ++ct) {
            const int c0 = chalf * 64 + ct * 16 + q * 4;   // c = c0 + reg
            uint2 w;
            w.x = (unsigned)f2bf(acv[ct][0]) | ((unsigned)f2bf(acv[ct][1]) << 16);
            w.y = (unsigned)f2bf(acv[ct][2]) | ((unsigned)f2bf(acv[ct][3]) << 16);
            *(uint2*)&sv[px * SVS + c0] = w;
        }
    }
#pragma unroll
    for (int t = 0; t < 8; ++t) {
        const int i4 = tid + t * NT;           // float4 index within Wv
        const int rr = i4 >> 5;                // row (32 float4 per 128-col row)
        const int cc = (i4 & 31) * 4;
        uint2 v;
        v.x = (unsigned)f2bf(wq[t].x) | ((unsigned)f2bf(wq[t].y) << 16);
        v.y = (unsigned)f2bf(wq[t].z) | ((unsigned)f2bf(wq[t].w) << 16);
        *(uint2*)&wvs[rr * WVS + cc] = v;
    }
    __syncthreads();  // B4

    // ---- P4: Wv-GEMM + residual epilogue (verbatim R5/R8; NT out stores) ----
    const int n = (y0 + row) * Wn + x0 + m16;
    const float g = gamma[0];

    short8 bfrag[4];
    {
        const unsigned short* srow = &sv[(row * 16 + m16) * SVS + q * 8];
#pragma unroll
        for (int kk = 0; kk < 4; ++kk) bfrag[kk] = *(const short8*)(srow + kk * 32);
    }
    f32x4 accv[4];
#pragma unroll
    for (int t = 0; t < 4; ++t) { f32x4 z = {0.f, 0.f, 0.f, 0.f}; accv[t] = z; }

#pragma unroll
    for (int t = 0; t < 4; ++t) {
        const int mg = chalf * 4 + t;
        const unsigned short* arow = &wvs[(mg * 16 + m16) * WVS + q * 8];
#pragma unroll
        for (int kk = 0; kk < 4; ++kk) {
            short8 af = *(const short8*)(arow + kk * 32);
            accv[t] = __builtin_amdgcn_mfma_f32_16x16x32_bf16(af, bfrag[kk], accv[t], 0, 0, 0);
        }
    }
#pragma unroll
    for (int t = 0; t < 4; ++t) {
        const int mg = chalf * 4 + t;
#pragma unroll
        for (int r = 0; r < 4; ++r) {
            const int c = mg * 16 + q * 4 + r;
            const size_t idx = ((size_t)(b * Cn + c)) * HWn + n;
            __builtin_nontemporal_store(fmap[idx] + g * accv[t][r], &out[idx]);
        }
    }
}
}  // namespace

extern "C" void kernel_launch(void* const* d_in, const int* in_sizes, int n_in,
                              void* d_out, int out_size, void* d_ws, size_t ws_size,
                              hipStream_t stream) {
    const float* attn  = (const float*)d_in[0];
    const float* fmap  = (const float*)d_in[1];
    const float* Wv    = (const float*)d_in[2];
    const float* gamma = (const float*)d_in[3];
    float* out = (float*)d_out;

    lsa_fused<<<dim3(512), NT, 0, stream>>>(attn, fmap, Wv, gamma, out);
}